// Round 1
// baseline (1765.654 us; speedup 1.0000x reference)
//
#include <hip/hip_runtime.h>
#include <hip/hip_bf16.h>

#define D 128

// ---------------- GEMM: A = emb @ W + bias  [N,128] ----------------
// 32 rows per block, 256 threads. W (64KB) + emb tile (16KB) in LDS.
__global__ __launch_bounds__(256) void gemm_bias(
    const float* __restrict__ emb, const float* __restrict__ W,
    const float* __restrict__ bias, float* __restrict__ A, int nNodes) {
  __shared__ float Ws[D * D];      // Ws[k*128+col]
  __shared__ float Es[32 * D];     // Es[r*128+k]
  const int tid = threadIdx.x;

  // stage W: 16384 floats = 4096 float4; 16 per thread
  const float4* W4 = (const float4*)W;
  float4* Ws4 = (float4*)Ws;
#pragma unroll
  for (int i = 0; i < 16; ++i) Ws4[tid + i * 256] = W4[tid + i * 256];

  const int row0 = blockIdx.x * 32;
  // stage 32 emb rows: 1024 float4; 4 per thread (guarded)
  float4* Es4 = (float4*)Es;
#pragma unroll
  for (int i = 0; i < 4; ++i) {
    int idx = tid + i * 256;           // float4 index within tile
    int r = row0 + (idx >> 5);         // 32 float4 per row
    float4 v = {0.f, 0.f, 0.f, 0.f};
    if (r < nNodes) v = ((const float4*)emb)[(size_t)r * 32 + (idx & 31)];
    Es4[idx] = v;
  }
  __syncthreads();

  const int col = tid & 127;
  const int rsub = tid >> 7;  // 0 or 1
  float acc[16];
#pragma unroll
  for (int r = 0; r < 16; ++r) acc[r] = 0.f;

  for (int k = 0; k < D; ++k) {
    float w = Ws[k * D + col];   // 2-way bank alias: free
#pragma unroll
    for (int r = 0; r < 16; ++r)
      acc[r] += Es[(r * 2 + rsub) * D + k] * w;  // wave-uniform: broadcast
  }

  float bc = bias[col];
#pragma unroll
  for (int r = 0; r < 16; ++r) {
    int row = row0 + r * 2 + rsub;
    if (row < nNodes) A[(size_t)row * D + col] = acc[r] + bc;
  }
}

// ---------------- SpMM scatter: B[rows[e]] += vals[e] * A[cols[e]] ----------------
// one wave per edge, 2 floats per lane
__global__ __launch_bounds__(256) void spmm_scatter(
    const float* __restrict__ A, const float* __restrict__ vals,
    const int* __restrict__ rows, const int* __restrict__ cols,
    float* __restrict__ B, int nEdges) {
  int e = blockIdx.x * 4 + (threadIdx.x >> 6);
  if (e >= nEdges) return;
  const int lane = threadIdx.x & 63;
  const int c = cols[e];
  const int r = rows[e];
  const float v = vals[e];
  float2 h2 = ((const float2*)(A + (size_t)c * D))[lane];
  float* dst = B + (size_t)r * D + lane * 2;
  atomicAdd(dst, v * h2.x);
  atomicAdd(dst + 1, v * h2.y);
}

// ---------------- relu + LayerNorm: A = LN(relu(B)) ----------------
// one wave per node, 2 elems/lane, shuffle reduce
__global__ __launch_bounds__(256) void relu_ln(
    const float* __restrict__ B, float* __restrict__ A,
    const float* __restrict__ gamma, const float* __restrict__ beta, int nNodes) {
  int node = blockIdx.x * 4 + (threadIdx.x >> 6);
  if (node >= nNodes) return;
  const int lane = threadIdx.x & 63;
  float2 v = ((const float2*)(B + (size_t)node * D))[lane];
  v.x = fmaxf(v.x, 0.f);
  v.y = fmaxf(v.y, 0.f);
  float s = v.x + v.y;
  float sq = v.x * v.x + v.y * v.y;
#pragma unroll
  for (int off = 32; off >= 1; off >>= 1) {
    s += __shfl_xor(s, off);
    sq += __shfl_xor(sq, off);
  }
  float mean = s * (1.f / 128.f);
  float var = sq * (1.f / 128.f) - mean * mean;
  float rstd = rsqrtf(var + 1e-5f);
  float2 g = ((const float2*)gamma)[lane];
  float2 be = ((const float2*)beta)[lane];
  float2 o;
  o.x = (v.x - mean) * rstd * g.x + be.x;
  o.y = (v.y - mean) * rstd * g.y + be.y;
  ((float2*)(A + (size_t)node * D))[lane] = o;
}

// ---------------- masked gather: out[b] = select ? A[x[b]-1] : 0 ----------------
// one float4 per thread
__global__ __launch_bounds__(256) void gather_out(
    const int* __restrict__ x, const float* __restrict__ A,
    float* __restrict__ out, int batch, int nNodes) {
  long gid = (long)blockIdx.x * 256 + threadIdx.x;
  int b = (int)(gid >> 5);
  int j = (int)(gid & 31);
  if (b >= batch) return;
  int xv = x[b];
  float4 res = {0.f, 0.f, 0.f, 0.f};
  if (xv >= 1 && xv <= nNodes) {
    res = ((const float4*)(A + (size_t)(xv - 1) * D))[j];
  }
  ((float4*)out)[gid] = res;
}

extern "C" void kernel_launch(void* const* d_in, const int* in_sizes, int n_in,
                              void* d_out, int out_size, void* d_ws, size_t ws_size,
                              hipStream_t stream) {
  const int* x = (const int*)d_in[0];
  const float* emb = (const float*)d_in[1];
  const float* W = (const float*)d_in[2];
  const float* bias = (const float*)d_in[3];
  const float* vals = (const float*)d_in[4];
  const int* rows = (const int*)d_in[5];
  const int* cols = (const int*)d_in[6];
  const float* gamma = (const float*)d_in[7];
  const float* beta = (const float*)d_in[8];
  float* out = (float*)d_out;

  const int batch = in_sizes[0];
  const int nNodes = in_sizes[1] / D;
  const int nEdges = in_sizes[4];

  float* A = (float*)d_ws;                       // [N,128] h0, later LN output
  float* B = A + (size_t)nNodes * D;             // [N,128] scatter accumulator

  hipMemsetAsync(B, 0, (size_t)nNodes * D * sizeof(float), stream);

  gemm_bias<<<(nNodes + 31) / 32, 256, 0, stream>>>(emb, W, bias, A, nNodes);
  spmm_scatter<<<(nEdges + 3) / 4, 256, 0, stream>>>(A, vals, rows, cols, B, nEdges);
  relu_ln<<<(nNodes + 3) / 4, 256, 0, stream>>>(B, A, gamma, beta, nNodes);
  long gthreads = (long)batch * 32;
  gather_out<<<(int)((gthreads + 255) / 256), 256, 0, stream>>>(x, A, out, batch, nNodes);
}

// Round 2
// 838.251 us; speedup vs baseline: 2.1064x; 2.1064x over previous
//
#include <hip/hip_runtime.h>
#include <hip/hip_bf16.h>

#define D 128

// ---------------- GEMM: A = emb @ W + bias  [N,128] ----------------
__global__ __launch_bounds__(256) void gemm_bias(
    const float* __restrict__ emb, const float* __restrict__ W,
    const float* __restrict__ bias, float* __restrict__ A, int nNodes) {
  __shared__ float Ws[D * D];      // Ws[k*128+col]
  __shared__ float Es[32 * D];     // Es[r*128+k]
  const int tid = threadIdx.x;

  const float4* W4 = (const float4*)W;
  float4* Ws4 = (float4*)Ws;
#pragma unroll
  for (int i = 0; i < 16; ++i) Ws4[tid + i * 256] = W4[tid + i * 256];

  const int row0 = blockIdx.x * 32;
  float4* Es4 = (float4*)Es;
#pragma unroll
  for (int i = 0; i < 4; ++i) {
    int idx = tid + i * 256;
    int r = row0 + (idx >> 5);
    float4 v = {0.f, 0.f, 0.f, 0.f};
    if (r < nNodes) v = ((const float4*)emb)[(size_t)r * 32 + (idx & 31)];
    Es4[idx] = v;
  }
  __syncthreads();

  const int col = tid & 127;
  const int rsub = tid >> 7;
  float acc[16];
#pragma unroll
  for (int r = 0; r < 16; ++r) acc[r] = 0.f;

  for (int k = 0; k < D; ++k) {
    float w = Ws[k * D + col];
#pragma unroll
    for (int r = 0; r < 16; ++r)
      acc[r] += Es[(r * 2 + rsub) * D + k] * w;
  }

  float bc = bias[col];
#pragma unroll
  for (int r = 0; r < 16; ++r) {
    int row = row0 + r * 2 + rsub;
    if (row < nNodes) A[(size_t)row * D + col] = acc[r] + bc;
  }
}

// ---------------- CSR build step 1: histogram of rows ----------------
__global__ __launch_bounds__(256) void hist_rows(
    const int* __restrict__ rows, int* __restrict__ cnt, int nEdges) {
  int e = blockIdx.x * 256 + threadIdx.x;
  if (e < nEdges) atomicAdd(&cnt[rows[e]], 1);
}

// ---------------- CSR build step 2: exclusive scan (single WG, 1024 thr) ----------------
// scans n = N+1 counters (cnt[N]==0) -> start[0..N]; also copies to cursor[0..nCur-1]
__global__ __launch_bounds__(1024) void scan_excl(
    const int* __restrict__ cnt, int* __restrict__ start, int* __restrict__ cursor,
    int n, int nCur) {
  __shared__ int wsum[16];
  __shared__ int wpre[16];
  const int tid = threadIdx.x;
  const int lane = tid & 63;
  const int wid = tid >> 6;
  int carry = 0;
  for (int base = 0; base < n; base += 1024) {
    int i = base + tid;
    int v = (i < n) ? cnt[i] : 0;
    int inc = v;
#pragma unroll
    for (int st = 1; st < 64; st <<= 1) {
      int t = __shfl_up(inc, st);
      if (lane >= st) inc += t;
    }
    if (lane == 63) wsum[wid] = inc;
    __syncthreads();
    if (tid < 16) {
      int wv = wsum[tid];
      int winc = wv;
#pragma unroll
      for (int st = 1; st < 16; st <<= 1) {
        int t = __shfl_up(winc, st);
        if (lane >= st) winc += t;
      }
      wpre[tid] = winc - wv;
    }
    __syncthreads();
    int excl = inc - v + wpre[wid] + carry;
    if (i < n) start[i] = excl;
    if (i < nCur) cursor[i] = excl;
    carry += wpre[15] + wsum[15];
    __syncthreads();
  }
}

// ---------------- CSR build step 3: scatter (col,val) into row-grouped order ----------------
__global__ __launch_bounds__(256) void scatter_build(
    const int* __restrict__ rows, const int* __restrict__ cols,
    const float* __restrict__ vals, int* __restrict__ cursor,
    int2* __restrict__ edata, int nEdges) {
  int e = blockIdx.x * 256 + threadIdx.x;
  if (e >= nEdges) return;
  int r = rows[e];
  int p = atomicAdd(&cursor[r], 1);
  int2 cv;
  cv.x = cols[e];
  cv.y = __float_as_int(vals[e]);
  edata[p] = cv;
}

// ---------------- segment sum + relu + LayerNorm fused ----------------
// one wave per row; lane holds cols {2*lane, 2*lane+1}
__global__ __launch_bounds__(256) void segsum_relu_ln(
    const float* __restrict__ A, const int2* __restrict__ edata,
    const int* __restrict__ start, const float* __restrict__ gamma,
    const float* __restrict__ beta, float* __restrict__ H, int nNodes) {
  int node = blockIdx.x * 4 + (threadIdx.x >> 6);
  if (node >= nNodes) return;
  const int lane = threadIdx.x & 63;
  int p = start[node];
  const int pend = start[node + 1];

  float2 acc = {0.f, 0.f};
  // software-pipelined: prefetch next edge's (col,val) while gathering current
  int2 cv = (p < pend) ? edata[p] : make_int2(0, 0);
  while (p < pend) {
    int2 cur = cv;
    ++p;
    if (p < pend) cv = edata[p];
    float v = __int_as_float(cur.y);
    float2 g = ((const float2*)(A + (size_t)cur.x * D))[lane];
    acc.x += v * g.x;
    acc.y += v * g.y;
  }

  // relu
  acc.x = fmaxf(acc.x, 0.f);
  acc.y = fmaxf(acc.y, 0.f);
  // LN reduction across 64 lanes (128 elems)
  float s = acc.x + acc.y;
  float sq = acc.x * acc.x + acc.y * acc.y;
#pragma unroll
  for (int off = 32; off >= 1; off >>= 1) {
    s += __shfl_xor(s, off);
    sq += __shfl_xor(sq, off);
  }
  float mean = s * (1.f / 128.f);
  float var = sq * (1.f / 128.f) - mean * mean;
  float rstd = rsqrtf(var + 1e-5f);
  float2 g = ((const float2*)gamma)[lane];
  float2 be = ((const float2*)beta)[lane];
  float2 o;
  o.x = (acc.x - mean) * rstd * g.x + be.x;
  o.y = (acc.y - mean) * rstd * g.y + be.y;
  ((float2*)(H + (size_t)node * D))[lane] = o;
}

// ---------------- fallback kernels (atomic path) ----------------
__global__ __launch_bounds__(256) void spmm_scatter(
    const float* __restrict__ A, const float* __restrict__ vals,
    const int* __restrict__ rows, const int* __restrict__ cols,
    float* __restrict__ B, int nEdges) {
  int e = blockIdx.x * 4 + (threadIdx.x >> 6);
  if (e >= nEdges) return;
  const int lane = threadIdx.x & 63;
  const int c = cols[e];
  const int r = rows[e];
  const float v = vals[e];
  float2 h2 = ((const float2*)(A + (size_t)c * D))[lane];
  float* dst = B + (size_t)r * D + lane * 2;
  atomicAdd(dst, v * h2.x);
  atomicAdd(dst + 1, v * h2.y);
}

__global__ __launch_bounds__(256) void relu_ln(
    const float* __restrict__ B, float* __restrict__ A,
    const float* __restrict__ gamma, const float* __restrict__ beta, int nNodes) {
  int node = blockIdx.x * 4 + (threadIdx.x >> 6);
  if (node >= nNodes) return;
  const int lane = threadIdx.x & 63;
  float2 v = ((const float2*)(B + (size_t)node * D))[lane];
  v.x = fmaxf(v.x, 0.f);
  v.y = fmaxf(v.y, 0.f);
  float s = v.x + v.y;
  float sq = v.x * v.x + v.y * v.y;
#pragma unroll
  for (int off = 32; off >= 1; off >>= 1) {
    s += __shfl_xor(s, off);
    sq += __shfl_xor(sq, off);
  }
  float mean = s * (1.f / 128.f);
  float var = sq * (1.f / 128.f) - mean * mean;
  float rstd = rsqrtf(var + 1e-5f);
  float2 g = ((const float2*)gamma)[lane];
  float2 be = ((const float2*)beta)[lane];
  float2 o;
  o.x = (v.x - mean) * rstd * g.x + be.x;
  o.y = (v.y - mean) * rstd * g.y + be.y;
  ((float2*)(A + (size_t)node * D))[lane] = o;
}

// ---------------- masked gather to output ----------------
__global__ __launch_bounds__(256) void gather_out(
    const int* __restrict__ x, const float* __restrict__ H,
    float* __restrict__ out, int batch, int nNodes) {
  long gid = (long)blockIdx.x * 256 + threadIdx.x;
  int b = (int)(gid >> 5);
  int j = (int)(gid & 31);
  if (b >= batch) return;
  int xv = x[b];
  float4 res = {0.f, 0.f, 0.f, 0.f};
  if (xv >= 1 && xv <= nNodes) {
    res = ((const float4*)(H + (size_t)(xv - 1) * D))[j];
  }
  ((float4*)out)[gid] = res;
}

extern "C" void kernel_launch(void* const* d_in, const int* in_sizes, int n_in,
                              void* d_out, int out_size, void* d_ws, size_t ws_size,
                              hipStream_t stream) {
  const int* x = (const int*)d_in[0];
  const float* emb = (const float*)d_in[1];
  const float* W = (const float*)d_in[2];
  const float* bias = (const float*)d_in[3];
  const float* vals = (const float*)d_in[4];
  const int* rows = (const int*)d_in[5];
  const int* cols = (const int*)d_in[6];
  const float* gamma = (const float*)d_in[7];
  const float* beta = (const float*)d_in[8];
  float* out = (float*)d_out;

  const int batch = in_sizes[0];
  const int nNodes = in_sizes[1] / D;
  const int nEdges = in_sizes[4];

  const size_t tabBytes = (size_t)nNodes * D * sizeof(float);       // 51.2 MB
  const size_t cntBytes = (((size_t)(nNodes + 1) * 4 + 15) / 16) * 16;
  const size_t curBytes = (((size_t)nNodes * 4 + 15) / 16) * 16;
  const size_t edBytes = (size_t)nEdges * 8;
  const size_t needCSR = 2 * tabBytes + 2 * cntBytes + curBytes + edBytes;

  uint8_t* p = (uint8_t*)d_ws;
  float* A = (float*)p; p += tabBytes;

  if (ws_size >= needCSR) {
    float* H = (float*)p; p += tabBytes;
    int* cnt = (int*)p; p += cntBytes;
    int* start = (int*)p; p += cntBytes;
    int* cursor = (int*)p; p += curBytes;
    int2* edata = (int2*)p;

    hipMemsetAsync(cnt, 0, (size_t)(nNodes + 1) * sizeof(int), stream);
    gemm_bias<<<(nNodes + 31) / 32, 256, 0, stream>>>(emb, W, bias, A, nNodes);
    hist_rows<<<(nEdges + 255) / 256, 256, 0, stream>>>(rows, cnt, nEdges);
    scan_excl<<<1, 1024, 0, stream>>>(cnt, start, cursor, nNodes + 1, nNodes);
    scatter_build<<<(nEdges + 255) / 256, 256, 0, stream>>>(rows, cols, vals, cursor, edata, nEdges);
    segsum_relu_ln<<<(nNodes + 3) / 4, 256, 0, stream>>>(A, edata, start, gamma, beta, H, nNodes);
    long gthreads = (long)batch * 32;
    gather_out<<<(int)((gthreads + 255) / 256), 256, 0, stream>>>(x, H, out, batch, nNodes);
  } else {
    // fallback: atomic scatter path
    float* B = (float*)p;
    hipMemsetAsync(B, 0, tabBytes, stream);
    gemm_bias<<<(nNodes + 31) / 32, 256, 0, stream>>>(emb, W, bias, A, nNodes);
    spmm_scatter<<<(nEdges + 3) / 4, 256, 0, stream>>>(A, vals, rows, cols, B, nEdges);
    relu_ln<<<(nNodes + 3) / 4, 256, 0, stream>>>(B, A, gamma, beta, nNodes);
    long gthreads = (long)batch * 32;
    gather_out<<<(int)((gthreads + 255) / 256), 256, 0, stream>>>(x, A, out, batch, nNodes);
  }
}

// Round 3
// 708.529 us; speedup vs baseline: 2.4920x; 1.1831x over previous
//
#include <hip/hip_runtime.h>
#include <hip/hip_bf16.h>

#define D 128

// ---- bf16 helpers (RNE pack, exact unpack) ----
__device__ inline unsigned short bf16rne(float f) {
  unsigned u = __float_as_uint(f);
  u += 0x7fff + ((u >> 16) & 1);
  return (unsigned short)(u >> 16);
}
__device__ inline float bf2f(unsigned short h) {
  return __uint_as_float(((unsigned)h) << 16);
}

// ---------------- GEMM: A16 = bf16(emb @ W + bias)  [N,128] ----------------
// 32 rows x 128 cols per block, 256 threads; thread = 8 rows x 2 cols.
__global__ __launch_bounds__(256) void gemm_bias(
    const float* __restrict__ emb, const float* __restrict__ W,
    const float* __restrict__ bias, unsigned int* __restrict__ A16u, int nNodes) {
  __shared__ float Ws[D * D];      // Ws[k*128+col]
  __shared__ float Es[32 * D];     // Es[r*128+k]
  const int tid = threadIdx.x;

  const float4* W4 = (const float4*)W;
  float4* Ws4 = (float4*)Ws;
#pragma unroll
  for (int i = 0; i < 16; ++i) Ws4[tid + i * 256] = W4[tid + i * 256];

  const int row0 = blockIdx.x * 32;
  float4* Es4s = (float4*)Es;
#pragma unroll
  for (int i = 0; i < 4; ++i) {
    int idx = tid + i * 256;
    int r = row0 + (idx >> 5);
    float4 v = {0.f, 0.f, 0.f, 0.f};
    if (r < nNodes) v = ((const float4*)emb)[(size_t)r * 32 + (idx & 31)];
    Es4s[idx] = v;
  }
  __syncthreads();

  const int cpair = tid & 63;   // cols 2*cpair, 2*cpair+1
  const int w = tid >> 6;       // wave: rows w*8 .. w*8+7
  float acc[8][2];
#pragma unroll
  for (int i = 0; i < 8; ++i) { acc[i][0] = 0.f; acc[i][1] = 0.f; }

  const float4* Es4 = (const float4*)Es;   // [32][32]
  const float2* Ws2 = (const float2*)Ws;   // [128][64]
  for (int k = 0; k < D; k += 4) {
    float4 e[8];
#pragma unroll
    for (int i = 0; i < 8; ++i) e[i] = Es4[(w * 8 + i) * 32 + (k >> 2)];
#pragma unroll
    for (int kk = 0; kk < 4; ++kk) {
      float2 wv = Ws2[(k + kk) * 64 + cpair];
#pragma unroll
      for (int i = 0; i < 8; ++i) {
        float ev = ((const float*)&e[i])[kk];
        acc[i][0] += ev * wv.x;
        acc[i][1] += ev * wv.y;
      }
    }
  }

  float2 b2 = ((const float2*)bias)[cpair];
#pragma unroll
  for (int i = 0; i < 8; ++i) {
    int row = row0 + w * 8 + i;
    if (row < nNodes) {
      unsigned lo = bf16rne(acc[i][0] + b2.x);
      unsigned hi = bf16rne(acc[i][1] + b2.y);
      A16u[(size_t)row * 64 + cpair] = lo | (hi << 16);
    }
  }
}

// ---------------- CSR build step 1: histogram of rows ----------------
__global__ __launch_bounds__(256) void hist_rows(
    const int* __restrict__ rows, int* __restrict__ cnt, int nEdges) {
  int e = blockIdx.x * 256 + threadIdx.x;
  if (e < nEdges) atomicAdd(&cnt[rows[e]], 1);
}

// ---------------- hierarchical exclusive scan ----------------
__global__ __launch_bounds__(1024) void scan_local(
    const int* __restrict__ cnt, int* __restrict__ start,
    int* __restrict__ bsum, int n) {
  __shared__ int wsum[16];
  __shared__ int wpre[16];
  const int tid = threadIdx.x;
  const int lane = tid & 63;
  const int wid = tid >> 6;
  int i = blockIdx.x * 1024 + tid;
  int v = (i < n) ? cnt[i] : 0;
  int inc = v;
#pragma unroll
  for (int st = 1; st < 64; st <<= 1) {
    int t = __shfl_up(inc, st);
    if (lane >= st) inc += t;
  }
  if (lane == 63) wsum[wid] = inc;
  __syncthreads();
  if (tid < 16) {
    int wv = wsum[tid];
    int winc = wv;
#pragma unroll
    for (int st = 1; st < 16; st <<= 1) {
      int t = __shfl_up(winc, st);
      if (lane >= st) winc += t;
    }
    wpre[tid] = winc - wv;
    if (tid == 15) bsum[blockIdx.x] = winc;
  }
  __syncthreads();
  if (i < n) start[i] = inc - v + wpre[wid];
}

// single block scans bsum[0..nb-1] exclusive, nb <= 1024
__global__ __launch_bounds__(1024) void scan_top(int* __restrict__ bsum, int nb) {
  __shared__ int wsum[16];
  __shared__ int wpre[16];
  const int tid = threadIdx.x;
  const int lane = tid & 63;
  const int wid = tid >> 6;
  int v = (tid < nb) ? bsum[tid] : 0;
  int inc = v;
#pragma unroll
  for (int st = 1; st < 64; st <<= 1) {
    int t = __shfl_up(inc, st);
    if (lane >= st) inc += t;
  }
  if (lane == 63) wsum[wid] = inc;
  __syncthreads();
  if (tid < 16) {
    int wv = wsum[tid];
    int winc = wv;
#pragma unroll
    for (int st = 1; st < 16; st <<= 1) {
      int t = __shfl_up(winc, st);
      if (lane >= st) winc += t;
    }
    wpre[tid] = winc - wv;
  }
  __syncthreads();
  if (tid < nb) bsum[tid] = inc - v + wpre[wid];
}

__global__ __launch_bounds__(1024) void scan_add(
    int* __restrict__ start, const int* __restrict__ bsum,
    int* __restrict__ cursor, int n, int nCur) {
  int i = blockIdx.x * 1024 + threadIdx.x;
  if (i < n) {
    int s = start[i] + bsum[blockIdx.x];
    start[i] = s;
    if (i < nCur) cursor[i] = s;
  }
}

// ---------------- CSR build step 3: scatter (col,val) into row-grouped order ----------------
__global__ __launch_bounds__(256) void scatter_build(
    const int* __restrict__ rows, const int* __restrict__ cols,
    const float* __restrict__ vals, int* __restrict__ cursor,
    int2* __restrict__ edata, int nEdges) {
  int e = blockIdx.x * 256 + threadIdx.x;
  if (e >= nEdges) return;
  int r = rows[e];
  int p = atomicAdd(&cursor[r], 1);
  int2 cv;
  cv.x = cols[e];
  cv.y = __float_as_int(vals[e]);
  edata[p] = cv;
}

// ---------------- segment sum + relu + LayerNorm fused (bf16 table in/out) ----------------
// one wave per row; 2 edges per iteration (half-wave each, float4/lane)
__global__ __launch_bounds__(256) void segsum_relu_ln(
    const unsigned short* __restrict__ A16, const int2* __restrict__ edata,
    const int* __restrict__ start, const float* __restrict__ gamma,
    const float* __restrict__ beta, unsigned short* __restrict__ H16, int nNodes) {
  int node = blockIdx.x * 4 + (threadIdx.x >> 6);
  if (node >= nNodes) return;
  const int lane = threadIdx.x & 63;
  const int half = lane >> 5;   // 0: even edges, 1: odd edges
  const int li = lane & 31;     // cols 4*li .. 4*li+3
  int p = start[node];
  const int pend = start[node + 1];

  float4 acc = {0.f, 0.f, 0.f, 0.f};
  for (; p < pend; p += 2) {
    int pp = p + half;
    int2 cv = (pp < pend) ? edata[pp] : make_int2(0, 0);
    float v = __int_as_float(cv.y);
    ushort4 u = ((const ushort4*)(A16 + (size_t)cv.x * D))[li];
    acc.x += v * bf2f(u.x);
    acc.y += v * bf2f(u.y);
    acc.z += v * bf2f(u.z);
    acc.w += v * bf2f(u.w);
  }
  // combine even/odd halves (lane i <-> i+32 hold same cols)
  acc.x += __shfl_xor(acc.x, 32);
  acc.y += __shfl_xor(acc.y, 32);
  acc.z += __shfl_xor(acc.z, 32);
  acc.w += __shfl_xor(acc.w, 32);

  // relu
  acc.x = fmaxf(acc.x, 0.f);
  acc.y = fmaxf(acc.y, 0.f);
  acc.z = fmaxf(acc.z, 0.f);
  acc.w = fmaxf(acc.w, 0.f);

  // LN reduction over 32 lanes (each half holds all 128 cols)
  float s = acc.x + acc.y + acc.z + acc.w;
  float sq = acc.x * acc.x + acc.y * acc.y + acc.z * acc.z + acc.w * acc.w;
#pragma unroll
  for (int off = 16; off >= 1; off >>= 1) {
    s += __shfl_xor(s, off);
    sq += __shfl_xor(sq, off);
  }
  float mean = s * (1.f / 128.f);
  float var = sq * (1.f / 128.f) - mean * mean;
  float rstd = rsqrtf(var + 1e-5f);

  float4 g = ((const float4*)gamma)[li];
  float4 be = ((const float4*)beta)[li];
  if (half == 0) {
    ushort4 o;
    o.x = bf16rne((acc.x - mean) * rstd * g.x + be.x);
    o.y = bf16rne((acc.y - mean) * rstd * g.y + be.y);
    o.z = bf16rne((acc.z - mean) * rstd * g.z + be.z);
    o.w = bf16rne((acc.w - mean) * rstd * g.w + be.w);
    ((ushort4*)(H16 + (size_t)node * D))[li] = o;
  }
}

// ---------------- masked gather to output (bf16 table -> fp32 out) ----------------
__global__ __launch_bounds__(256) void gather_out(
    const int* __restrict__ x, const unsigned short* __restrict__ H16,
    float* __restrict__ out, int batch, int nNodes) {
  long gid = (long)blockIdx.x * 256 + threadIdx.x;
  int b = (int)(gid >> 5);
  int j = (int)(gid & 31);
  if (b >= batch) return;
  int xv = x[b];
  float4 res = {0.f, 0.f, 0.f, 0.f};
  if (xv >= 1 && xv <= nNodes) {
    ushort4 u = ((const ushort4*)(H16 + (size_t)(xv - 1) * D))[j];
    res.x = bf2f(u.x);
    res.y = bf2f(u.y);
    res.z = bf2f(u.z);
    res.w = bf2f(u.w);
  }
  ((float4*)out)[gid] = res;
}

extern "C" void kernel_launch(void* const* d_in, const int* in_sizes, int n_in,
                              void* d_out, int out_size, void* d_ws, size_t ws_size,
                              hipStream_t stream) {
  const int* x = (const int*)d_in[0];
  const float* emb = (const float*)d_in[1];
  const float* W = (const float*)d_in[2];
  const float* bias = (const float*)d_in[3];
  const float* vals = (const float*)d_in[4];
  const int* rows = (const int*)d_in[5];
  const int* cols = (const int*)d_in[6];
  const float* gamma = (const float*)d_in[7];
  const float* beta = (const float*)d_in[8];
  float* out = (float*)d_out;

  const int batch = in_sizes[0];
  const int nNodes = in_sizes[1] / D;
  const int nEdges = in_sizes[4];
  const int n1 = nNodes + 1;
  const int nb = (n1 + 1023) / 1024;

  const size_t tab16 = (((size_t)nNodes * D * 2 + 255) / 256) * 256;  // bf16 table
  const size_t cntB = (((size_t)n1 * 4 + 255) / 256) * 256;
  const size_t curB = (((size_t)nNodes * 4 + 255) / 256) * 256;
  const size_t bsB = (((size_t)nb * 4 + 255) / 256) * 256;

  uint8_t* p = (uint8_t*)d_ws;
  unsigned short* A16 = (unsigned short*)p; p += tab16;
  unsigned short* H16 = (unsigned short*)p; p += tab16;
  int* cnt = (int*)p; p += cntB;
  int* start = (int*)p; p += cntB;
  int* cursor = (int*)p; p += curB;
  int* bsum = (int*)p; p += bsB;
  int2* edata = (int2*)p;

  hipMemsetAsync(cnt, 0, (size_t)n1 * sizeof(int), stream);
  gemm_bias<<<(nNodes + 31) / 32, 256, 0, stream>>>(emb, W, bias, (unsigned int*)A16, nNodes);
  hist_rows<<<(nEdges + 255) / 256, 256, 0, stream>>>(rows, cnt, nEdges);
  scan_local<<<nb, 1024, 0, stream>>>(cnt, start, bsum, n1);
  scan_top<<<1, 1024, 0, stream>>>(bsum, nb);
  scan_add<<<nb, 1024, 0, stream>>>(start, bsum, cursor, n1, nNodes);
  scatter_build<<<(nEdges + 255) / 256, 256, 0, stream>>>(rows, cols, vals, cursor, edata, nEdges);
  segsum_relu_ln<<<(nNodes + 3) / 4, 256, 0, stream>>>(A16, edata, start, gamma, beta, H16, nNodes);
  long gthreads = (long)batch * 32;
  gather_out<<<(int)((gthreads + 255) / 256), 256, 0, stream>>>(x, H16, out, batch, nNodes);
}

// Round 4
// 617.028 us; speedup vs baseline: 2.8615x; 1.1483x over previous
//
#include <hip/hip_runtime.h>
#include <hip/hip_bf16.h>

#define D 128

typedef __attribute__((ext_vector_type(8))) short s8v;    // 8 bf16 (4 VGPRs)
typedef __attribute__((ext_vector_type(4))) float f4v;    // MFMA acc

// ---- bf16 helpers (RNE pack, exact unpack) ----
__device__ inline unsigned short bf16rne(float f) {
  unsigned u = __float_as_uint(f);
  u += 0x7fff + ((u >> 16) & 1);
  return (unsigned short)(u >> 16);
}
__device__ inline float bf2f(unsigned short h) {
  return __uint_as_float(((unsigned)h) << 16);
}

// ---------------- fused: MFMA GEMM (A16 = bf16(emb@W+bias)) + row histogram ----------------
// gemm blocks: 64 rows x 128 cols, 4 waves, wave = 16 rows (8 n-tiles of 16x16x32 MFMA).
// blocks >= gemmBlocks do the edge-row histogram instead (independent work, overlapped).
#define WT_STRIDE 136   // bf16 elems per row (128 + 8 pad) -> 16B-aligned b128 reads
__global__ __launch_bounds__(256) void gemm_hist(
    const float* __restrict__ emb, const float* __restrict__ W,
    const float* __restrict__ bias, unsigned short* __restrict__ A16,
    int nNodes, int gemmBlocks,
    const int* __restrict__ rows, int* __restrict__ cnt, int nEdges) {
  if ((int)blockIdx.x >= gemmBlocks) {
    int e = ((int)blockIdx.x - gemmBlocks) * 256 + threadIdx.x;
    if (e < nEdges) atomicAdd(&cnt[rows[e]], 1);
    return;
  }
  __shared__ unsigned short WT[128 * WT_STRIDE];  // W^T: WT[n][k], bf16
  const int tid = threadIdx.x;
#pragma unroll
  for (int i = 0; i < 64; ++i) {
    int idx = tid + i * 256;            // 16384 elems, coalesced global read
    int k = idx >> 7, n = idx & 127;
    WT[n * WT_STRIDE + k] = bf16rne(W[idx]);
  }
  __syncthreads();

  const int w = tid >> 6;          // wave 0..3
  const int lane = tid & 63;
  const int m = lane & 15;         // A row / D col index within tile
  const int kb = lane >> 4;        // k-block 0..3 (8 elems each)
  const int r0 = (int)blockIdx.x * 64 + w * 16;
  int rowA = r0 + m;
  if (rowA > nNodes - 1) rowA = nNodes - 1;      // clamp; stores are guarded
  const float* arow = emb + (size_t)rowA * D + kb * 8;

  f4v acc[8];
#pragma unroll
  for (int t = 0; t < 8; ++t) acc[t] = (f4v){0.f, 0.f, 0.f, 0.f};

#pragma unroll
  for (int ks = 0; ks < 4; ++ks) {
    const int k0 = ks * 32;
    float4 a0 = *(const float4*)(arow + k0);
    float4 a1 = *(const float4*)(arow + k0 + 4);
    s8v af;
    af[0] = (short)bf16rne(a0.x); af[1] = (short)bf16rne(a0.y);
    af[2] = (short)bf16rne(a0.z); af[3] = (short)bf16rne(a0.w);
    af[4] = (short)bf16rne(a1.x); af[5] = (short)bf16rne(a1.y);
    af[6] = (short)bf16rne(a1.z); af[7] = (short)bf16rne(a1.w);
#pragma unroll
    for (int nt = 0; nt < 8; ++nt) {
      int n = nt * 16 + m;
      s8v bf = *(const s8v*)&WT[n * WT_STRIDE + k0 + kb * 8];
      acc[nt] = __builtin_amdgcn_mfma_f32_16x16x32_bf16(af, bf, acc[nt], 0, 0, 0);
    }
  }

  // epilogue: D mapping col=lane&15, row=(lane>>4)*4+reg
#pragma unroll
  for (int nt = 0; nt < 8; ++nt) {
    int col = nt * 16 + m;
    float bcol = bias[col];
#pragma unroll
    for (int reg = 0; reg < 4; ++reg) {
      int row = r0 + kb * 4 + reg;
      if (row < nNodes)
        A16[(size_t)row * D + col] = bf16rne(acc[nt][reg] + bcol);
    }
  }
}

// ---------------- hierarchical exclusive scan ----------------
__global__ __launch_bounds__(1024) void scan_local(
    const int* __restrict__ cnt, int* __restrict__ start,
    int* __restrict__ bsum, int n) {
  __shared__ int wsum[16];
  __shared__ int wpre[16];
  const int tid = threadIdx.x;
  const int lane = tid & 63;
  const int wid = tid >> 6;
  int i = blockIdx.x * 1024 + tid;
  int v = (i < n) ? cnt[i] : 0;
  int inc = v;
#pragma unroll
  for (int st = 1; st < 64; st <<= 1) {
    int t = __shfl_up(inc, st);
    if (lane >= st) inc += t;
  }
  if (lane == 63) wsum[wid] = inc;
  __syncthreads();
  if (tid < 16) {
    int wv = wsum[tid];
    int winc = wv;
#pragma unroll
    for (int st = 1; st < 16; st <<= 1) {
      int t = __shfl_up(winc, st);
      if (lane >= st) winc += t;
    }
    wpre[tid] = winc - wv;
    if (tid == 15) bsum[blockIdx.x] = winc;
  }
  __syncthreads();
  if (i < n) start[i] = inc - v + wpre[wid];
}

__global__ __launch_bounds__(1024) void scan_top(int* __restrict__ bsum, int nb) {
  __shared__ int wsum[16];
  __shared__ int wpre[16];
  const int tid = threadIdx.x;
  const int lane = tid & 63;
  const int wid = tid >> 6;
  int v = (tid < nb) ? bsum[tid] : 0;
  int inc = v;
#pragma unroll
  for (int st = 1; st < 64; st <<= 1) {
    int t = __shfl_up(inc, st);
    if (lane >= st) inc += t;
  }
  if (lane == 63) wsum[wid] = inc;
  __syncthreads();
  if (tid < 16) {
    int wv = wsum[tid];
    int winc = wv;
#pragma unroll
    for (int st = 1; st < 16; st <<= 1) {
      int t = __shfl_up(winc, st);
      if (lane >= st) winc += t;
    }
    wpre[tid] = winc - wv;
  }
  __syncthreads();
  if (tid < nb) bsum[tid] = inc - v + wpre[wid];
}

__global__ __launch_bounds__(1024) void scan_add(
    int* __restrict__ start, const int* __restrict__ bsum,
    int* __restrict__ cursor, int n, int nCur) {
  int i = blockIdx.x * 1024 + threadIdx.x;
  if (i < n) {
    int s = start[i] + bsum[blockIdx.x];
    start[i] = s;
    if (i < nCur) cursor[i] = s;
  }
}

// ---------------- CSR build: scatter (col,val) into row-grouped order ----------------
__global__ __launch_bounds__(256) void scatter_build(
    const int* __restrict__ rows, const int* __restrict__ cols,
    const float* __restrict__ vals, int* __restrict__ cursor,
    int2* __restrict__ edata, int nEdges) {
  int e = blockIdx.x * 256 + threadIdx.x;
  if (e >= nEdges) return;
  int r = rows[e];
  int p = atomicAdd(&cursor[r], 1);
  int2 cv;
  cv.x = cols[e];
  cv.y = __float_as_int(vals[e]);
  edata[p] = cv;
}

// ---------------- segment sum + relu + LayerNorm (bf16 table), 4 edges/iter ----------------
// one wave per row; 4 subgroups of 16 lanes, each subgroup handles one edge (16B/lane).
__global__ __launch_bounds__(256) void segsum_relu_ln(
    const unsigned short* __restrict__ A16, const int2* __restrict__ edata,
    const int* __restrict__ start, const float* __restrict__ gamma,
    const float* __restrict__ beta, unsigned short* __restrict__ H16, int nNodes) {
  int node = blockIdx.x * 4 + (threadIdx.x >> 6);
  if (node >= nNodes) return;
  const int lane = threadIdx.x & 63;
  const int g = lane >> 4;       // edge subgroup
  const int li = lane & 15;      // col chunk: cols 8*li .. 8*li+7
  int p = start[node];
  const int pend = start[node + 1];

  float acc[8];
#pragma unroll
  for (int j = 0; j < 8; ++j) acc[j] = 0.f;

  for (; p < pend; p += 4) {
    int pp = p + g;
    int2 cv = make_int2(0, 0);
    if (pp < pend) cv = edata[pp];          // broadcast within subgroup
    float v = __int_as_float(cv.y);          // v==0 for pad -> no-op
    uint4 u = ((const uint4*)(A16 + (size_t)cv.x * D))[li];
    acc[0] += v * bf2f((unsigned short)(u.x & 0xffff));
    acc[1] += v * bf2f((unsigned short)(u.x >> 16));
    acc[2] += v * bf2f((unsigned short)(u.y & 0xffff));
    acc[3] += v * bf2f((unsigned short)(u.y >> 16));
    acc[4] += v * bf2f((unsigned short)(u.z & 0xffff));
    acc[5] += v * bf2f((unsigned short)(u.z >> 16));
    acc[6] += v * bf2f((unsigned short)(u.w & 0xffff));
    acc[7] += v * bf2f((unsigned short)(u.w >> 16));
  }
  // combine the 4 subgroups (lanes with equal li hold the same cols)
#pragma unroll
  for (int j = 0; j < 8; ++j) {
    acc[j] += __shfl_xor(acc[j], 16);
    acc[j] += __shfl_xor(acc[j], 32);
  }
  // relu + LN stats
  float s = 0.f, sq = 0.f;
#pragma unroll
  for (int j = 0; j < 8; ++j) {
    acc[j] = fmaxf(acc[j], 0.f);
    s += acc[j];
    sq += acc[j] * acc[j];
  }
#pragma unroll
  for (int off = 8; off >= 1; off >>= 1) {
    s += __shfl_xor(s, off);
    sq += __shfl_xor(sq, off);
  }
  float mean = s * (1.f / 128.f);
  float var = sq * (1.f / 128.f) - mean * mean;
  float rstd = rsqrtf(var + 1e-5f);

  float4 g0 = ((const float4*)gamma)[li * 2];
  float4 g1 = ((const float4*)gamma)[li * 2 + 1];
  float4 b0 = ((const float4*)beta)[li * 2];
  float4 b1 = ((const float4*)beta)[li * 2 + 1];
  if (g == 0) {
    unsigned o0 = bf16rne((acc[0] - mean) * rstd * g0.x + b0.x)
                | ((unsigned)bf16rne((acc[1] - mean) * rstd * g0.y + b0.y) << 16);
    unsigned o1 = bf16rne((acc[2] - mean) * rstd * g0.z + b0.z)
                | ((unsigned)bf16rne((acc[3] - mean) * rstd * g0.w + b0.w) << 16);
    unsigned o2 = bf16rne((acc[4] - mean) * rstd * g1.x + b1.x)
                | ((unsigned)bf16rne((acc[5] - mean) * rstd * g1.y + b1.y) << 16);
    unsigned o3 = bf16rne((acc[6] - mean) * rstd * g1.z + b1.z)
                | ((unsigned)bf16rne((acc[7] - mean) * rstd * g1.w + b1.w) << 16);
    uint4 o = make_uint4(o0, o1, o2, o3);
    ((uint4*)(H16 + (size_t)node * D))[li] = o;
  }
}

// ---------------- masked gather to output (bf16 table -> fp32 out, NT stores) ----------------
__global__ __launch_bounds__(256) void gather_out(
    const int* __restrict__ x, const unsigned short* __restrict__ H16,
    float* __restrict__ out, int batch, int nNodes) {
  long gid = (long)blockIdx.x * 256 + threadIdx.x;
  int b = (int)(gid >> 5);
  int j = (int)(gid & 31);
  if (b >= batch) return;
  int xv = x[b];
  f4v res = (f4v){0.f, 0.f, 0.f, 0.f};
  if (xv >= 1 && xv <= nNodes) {
    ushort4 u = ((const ushort4*)(H16 + (size_t)(xv - 1) * D))[j];
    res = (f4v){bf2f(u.x), bf2f(u.y), bf2f(u.z), bf2f(u.w)};
  }
  __builtin_nontemporal_store(res, (f4v*)out + gid);
}

extern "C" void kernel_launch(void* const* d_in, const int* in_sizes, int n_in,
                              void* d_out, int out_size, void* d_ws, size_t ws_size,
                              hipStream_t stream) {
  const int* x = (const int*)d_in[0];
  const float* emb = (const float*)d_in[1];
  const float* W = (const float*)d_in[2];
  const float* bias = (const float*)d_in[3];
  const float* vals = (const float*)d_in[4];
  const int* rows = (const int*)d_in[5];
  const int* cols = (const int*)d_in[6];
  const float* gamma = (const float*)d_in[7];
  const float* beta = (const float*)d_in[8];
  float* out = (float*)d_out;

  const int batch = in_sizes[0];
  const int nNodes = in_sizes[1] / D;
  const int nEdges = in_sizes[4];
  const int n1 = nNodes + 1;
  const int nb = (n1 + 1023) / 1024;

  const size_t tab16 = (((size_t)nNodes * D * 2 + 255) / 256) * 256;
  const size_t cntB = (((size_t)n1 * 4 + 255) / 256) * 256;
  const size_t curB = (((size_t)nNodes * 4 + 255) / 256) * 256;
  const size_t bsB = (((size_t)nb * 4 + 255) / 256) * 256;

  uint8_t* p = (uint8_t*)d_ws;
  unsigned short* A16 = (unsigned short*)p; p += tab16;
  unsigned short* H16 = (unsigned short*)p; p += tab16;
  int* cnt = (int*)p; p += cntB;
  int* start = (int*)p; p += cntB;
  int* cursor = (int*)p; p += curB;
  int* bsum = (int*)p; p += bsB;
  int2* edata = (int2*)p;

  const int gemmBlocks = (nNodes + 63) / 64;
  const int histBlocks = (nEdges + 255) / 256;

  hipMemsetAsync(cnt, 0, (size_t)n1 * sizeof(int), stream);
  gemm_hist<<<gemmBlocks + histBlocks, 256, 0, stream>>>(
      emb, W, bias, A16, nNodes, gemmBlocks, rows, cnt, nEdges);
  scan_local<<<nb, 1024, 0, stream>>>(cnt, start, bsum, n1);
  scan_top<<<1, 1024, 0, stream>>>(bsum, nb);
  scan_add<<<nb, 1024, 0, stream>>>(start, bsum, cursor, n1, nNodes);
  scatter_build<<<(nEdges + 255) / 256, 256, 0, stream>>>(rows, cols, vals, cursor, edata, nEdges);
  segsum_relu_ln<<<(nNodes + 3) / 4, 256, 0, stream>>>(A16, edata, start, gamma, beta, H16, nNodes);
  long gthreads = (long)batch * 32;
  gather_out<<<(int)((gthreads + 255) / 256), 256, 0, stream>>>(x, H16, out, batch, nNodes);
}